// Round 8
// baseline (1271.982 us; speedup 1.0000x reference)
//
#include <hip/hip_runtime.h>

#define NB 16
#define NC 256
#define NH 64
#define NW 64
#define NK 1024
#define HW (NH * NW)          // 4096
#define NPOS (NB * HW)        // 65536
#define NOUT (NB * NC * HW)   // 16777216
#define NSLOT 256             // loss accumulator slots (atomic spreading)
#define TP 32                 // positions per block

__device__ __forceinline__ float sq_rn(float x) { return __fmul_rn(x, x); }

// Exact replica of numpy pairwise_sum for sum(a*a) over n=256 (verified R2/R4).
__device__ __forceinline__ float pairwise_sumsq_256(const float* __restrict__ a,
                                                    int stride) {
    float s_half[2];
#pragma unroll
    for (int h = 0; h < 2; ++h) {
        const float* base = a + (size_t)(h * 128) * stride;
        float r[8];
#pragma unroll
        for (int j = 0; j < 8; ++j) r[j] = sq_rn(base[(size_t)j * stride]);
        for (int i = 8; i < 128; i += 8) {
#pragma unroll
            for (int j = 0; j < 8; ++j)
                r[j] = __fadd_rn(r[j], sq_rn(base[(size_t)(i + j) * stride]));
        }
        s_half[h] = __fadd_rn(
            __fadd_rn(__fadd_rn(r[0], r[1]), __fadd_rn(r[2], r[3])),
            __fadd_rn(__fadd_rn(r[4], r[5]), __fadd_rn(r[6], r[7])));
    }
    return __fadd_rn(s_half[0], s_half[1]);
}

// ---------------------------------------------------------------------------
// Kernel A: cnorm[k] = numpy-fp32 sum(codebook[k]^2)
// ---------------------------------------------------------------------------
__global__ __launch_bounds__(256) void cnorm_kernel(const float* __restrict__ cb,
                                                    float* __restrict__ cnorm) {
    int k = blockIdx.x * 256 + threadIdx.x;
    if (k < NK) {
        cnorm[k] = pairwise_sumsq_256(cb + (size_t)k * NC, 1);
    }
}

// ---------------------------------------------------------------------------
// Kernel A2 (R12, kept): q-major packed codebook.
// Blocks of 128 codes; code k at slot (k&7)*16+((k>>3)&15); per 4-dim chunk
// `it`: cbT3[it][kblk][slot][4]. In argmin, load-instruction q across the 16
// cg-lanes reads 256 contiguous bytes (4 lines) — coalesced.
// ---------------------------------------------------------------------------
__global__ __launch_bounds__(256) void pack_cb_kernel(const float* __restrict__ cb,
                                                      float* __restrict__ cbT3) {
    const int k = blockIdx.x;    // 0..1023
    const int d = threadIdx.x;   // 0..255
    const int it = d >> 2, dl = d & 3;
    const int kb = k >> 7;               // 128-code block
    const int q = k & 7;                 // code-within-thread
    const int cgi = (k >> 3) & 15;       // cg lane
    cbT3[(size_t)(((it * 8 + kb) * 128) + q * 16 + cgi) * 4 + dl] =
        cb[(size_t)k * NC + d];
}

// ---------------------------------------------------------------------------
// R13/R14 helpers: 8-load prefetch + 4-dim FMA chunk (named buffers, rule #20).
// ---------------------------------------------------------------------------
__device__ __forceinline__ void load8(float4* __restrict__ buf,
                                      const float* __restrict__ cp3, int itx) {
#pragma unroll
    for (int q = 0; q < 8; ++q)
        buf[q] = *(const float4*)(cp3 + (size_t)itx * 4096 + q * 64);
}

__device__ __forceinline__ void compute_it(const float4* __restrict__ cbuf,
                                           float acc[8][8],
                                           const float (*z_lds)[TP],
                                           int it, int pg) {
#pragma unroll
    for (int dl = 0; dl < 4; ++dl) {
        const int d = it * 4 + dl;
        const float4 za = *(const float4*)&z_lds[d][pg * 8];
        const float4 zb = *(const float4*)&z_lds[d][pg * 8 + 4];
        const float zf[8] = {za.x, za.y, za.z, za.w, zb.x, zb.y, zb.z, zb.w};
#pragma unroll
        for (int i = 0; i < 8; ++i)
#pragma unroll
            for (int j = 0; j < 8; ++j)
                acc[i][j] = __fmaf_rn(zf[i], ((const float*)&cbuf[j])[dl],
                                      acc[i][j]);
    }
}

// ---------------------------------------------------------------------------
// Kernel B (R14 = R13 resubmitted after infra failure; audited hang-free:
// the pass-0 __syncthreads is uniform, znorm_s race-free, sched_barrier is
// compile-time only):
// R12 post-mortem: coalescing worked (bank-conflicts 0) but 35% idle remains;
// VGPR=80 shows loads collapsed to just-before-use, and dl=0 needs ALL 8
// loads -> full L2 latency exposed once per it, covered only by TLP.
// R14: (a) explicit 2-it ping-pong bufA/bufB with sched_barrier(0) pinning
// prefetch issue above the FMA cluster (prevents the R7/R11/R12 collapse);
// launch_bounds(256,3) caps VGPR ~170 vs demand ~155 -> no forced spill
// (R8 lesson), >=3 waves/SIMD. (b) znorm computed from z_lds (same bits ->
// bit-exact) by wave 0 only, halves split across lane pairs (exact add tree,
// one shfl combine); consumer sync deferred to a single pass-0 barrier
// before the score section -> znorm cost fully hidden under the inner loop.
// Bit-exact: same sequential __fmaf_rn chain over ascending d; score =
// fl(fl(zn+cn)-2*dot); per-thread k ascending across passes; tie-breaks in
// both reduces. Fused gather/loss kept.
// ---------------------------------------------------------------------------
__global__ __launch_bounds__(256, 3) void argmin_kernel(const float* __restrict__ z,
                                                        const float* __restrict__ cb,
                                                        const float* __restrict__ cbT3,
                                                        const float* __restrict__ cnorm,
                                                        float* __restrict__ out,
                                                        float* __restrict__ idx_out,
                                                        double* __restrict__ loss_acc) {
    __shared__ float z_lds[256][TP];      // 32768 B, [d][p] == [c][p]
    __shared__ float znorm_s[TP];         //   128 B
    __shared__ float red_v[4][TP];        //   512 B
    __shared__ int   red_i[4][TP];        //   512 B   -> ~34 KB, 4 blk/CU

    const int blk = blockIdx.x;           // 0..2047
    const int b = blk >> 7;               // batch (128 tiles per batch)
    const int hw0 = (blk & 127) * TP;     // tile base (32 contiguous positions)
    const int t = threadIdx.x;            // 0..255
    const int lane = t & 63;
    const int wave = t >> 6;              // 0..3
    const int pg = lane >> 4;             // position group: 4 groups x 8 pos
    const int cg = lane & 15;             // code group: 16 groups x 8 codes

    const float* zg = z + (size_t)b * (NC * HW) + hw0;

    // ---- stage z d-major: 256x32 floats = 2048 float4 over 256 threads
#pragma unroll
    for (int i = 0; i < 8; ++i) {
        const int d = i * 32 + (t >> 3);
        const int p = (t & 7) * 4;
        const float4 v = *(const float4*)(zg + (size_t)d * HW + p);
        *(float4*)&z_lds[d][p] = v;
    }
    __syncthreads();                      // z_lds ready (everyone needs it)

    // ---- znorm from z_lds (same bits as global z -> bit-exact), wave 0 only.
    //      Lane pair (2p, 2p+1) computes the two pairwise halves of position
    //      p: identical add tree to pairwise_sumsq_256, halves combined with
    //      the same final __fadd_rn via shfl. Other waves proceed straight
    //      into the inner loop; sync deferred to the pass-0 score barrier.
    if (t < 64) {
        const int p = t >> 1;
        const int h = t & 1;
        const float* base = &z_lds[h * 128][p];   // stride TP floats
        float r[8];
#pragma unroll
        for (int j = 0; j < 8; ++j) r[j] = sq_rn(base[(size_t)j * TP]);
        for (int i = 8; i < 128; i += 8) {
#pragma unroll
            for (int j = 0; j < 8; ++j)
                r[j] = __fadd_rn(r[j], sq_rn(base[(size_t)(i + j) * TP]));
        }
        const float s = __fadd_rn(
            __fadd_rn(__fadd_rn(r[0], r[1]), __fadd_rn(r[2], r[3])),
            __fadd_rn(__fadd_rn(r[4], r[5]), __fadd_rn(r[6], r[7])));
        const float other = __shfl_down(s, 1, 64);
        if (h == 0) znorm_s[p] = __fadd_rn(s, other);
    }

    float best[8];
    int bid[8];
#pragma unroll
    for (int i = 0; i < 8; ++i) { best[i] = 3.4e38f; bid[i] = 0; }

#pragma unroll 1
    for (int pass = 0; pass < 2; ++pass) {
        float acc[8][8];
#pragma unroll
        for (int i = 0; i < 8; ++i)
#pragma unroll
            for (int j = 0; j < 8; ++j) acc[i][j] = 0.f;

        // wave owns codes [wave*256, +256); this pass: 16 cgs x 8 codes = 128.
        const int k0 = wave * 256 + pass * 128 + cg * 8;
        const float* cp3 = cbT3 + (size_t)((wave * 2 + pass) * 512 + cg * 4);

        float4 bufA[8], bufB[8];
        load8(bufA, cp3, 0);
#pragma unroll 1
        for (int itp = 0; itp < 32; ++itp) {
            const int it0 = itp * 2;
            load8(bufB, cp3, it0 + 1);            // prefetch next
            __builtin_amdgcn_sched_barrier(0);    // pin issue above FMAs
            compute_it(bufA, acc, z_lds, it0, pg);
            if (itp < 31) load8(bufA, cp3, it0 + 2);
            __builtin_amdgcn_sched_barrier(0);
            compute_it(bufB, acc, z_lds, it0 + 1, pg);
        }

        // scores for this pass's 8 codes (k ascending within thread across
        // passes -> strict < keeps first occurrence)
        if (pass == 0) __syncthreads();   // uniform; publishes znorm_s
        const float4 cn0 = *(const float4*)(cnorm + k0);
        const float4 cn1 = *(const float4*)(cnorm + k0 + 4);
        const float cnf[8] = {cn0.x, cn0.y, cn0.z, cn0.w,
                              cn1.x, cn1.y, cn1.z, cn1.w};
        float znl[8];
#pragma unroll
        for (int i = 0; i < 8; ++i) znl[i] = znorm_s[pg * 8 + i];
#pragma unroll
        for (int j = 0; j < 8; ++j) {
            const int k = k0 + j;
#pragma unroll
            for (int i = 0; i < 8; ++i) {
                const float sc = __fsub_rn(__fadd_rn(znl[i], cnf[j]),
                                           __fmul_rn(2.0f, acc[i][j]));
                if (sc < best[i]) { best[i] = sc; bid[i] = k; }
            }
        }
    }

    // ---- reduce across the 16 cg-lanes of each pg group (offsets 8,4,2,1).
    //      Lanes whose shuffle source crosses the 16-lane group get garbage,
    //      but those lanes never feed lane cg==0's final value. k-ranges of
    //      different cgs INTERLEAVE across passes -> tie-break on lower index
    //      to match np.argmin first-occurrence.
#pragma unroll
    for (int off = 8; off >= 1; off >>= 1) {
#pragma unroll
        for (int i = 0; i < 8; ++i) {
            const float v = __shfl_down(best[i], off, 64);
            const int d2 = __shfl_down(bid[i], off, 64);
            if (v < best[i] || (v == best[i] && d2 < bid[i])) {
                best[i] = v;
                bid[i] = d2;
            }
        }
    }
    if (cg == 0) {
#pragma unroll
        for (int i = 0; i < 8; ++i) {
            red_v[wave][pg * 8 + i] = best[i];
            red_i[wave][pg * 8 + i] = bid[i];
        }
    }
    __syncthreads();

    // ---- final reduce across 4 waves (disjoint ascending k ranges); publish
    //      final idx in red_i[0][p]
    if (t < TP) {
        float bv = red_v[0][t];
        int bi = red_i[0][t];
#pragma unroll
        for (int w = 1; w < 4; ++w) {
            const float v = red_v[w][t];
            const int i2 = red_i[w][t];
            if (v < bv || (v == bv && i2 < bi)) { bv = v; bi = i2; }
        }
        idx_out[b * HW + hw0 + t] = (float)bi;
        red_i[0][t] = bi;                 // each t touches only column t: safe
    }
    __syncthreads();

    // ---- fused gather + loss: out[b][c][hw0+p] = cb[idx[p]][c];
    //      z_lds[c][p] still holds z for this tile (same bits as global z).
    float* outg = out + (size_t)b * (NC * HW) + hw0;
    float lsum = 0.f;
#pragma unroll 1
    for (int r = 0; r < 8; ++r) {
        const int id = r * 256 + t;       // 0..2047 = [c 0..255][p4 0..7]
        const int c = id >> 3;
        const int p4 = (id & 7) * 4;
        const int i0 = red_i[0][p4];
        const int i1 = red_i[0][p4 + 1];
        const int i2 = red_i[0][p4 + 2];
        const int i3 = red_i[0][p4 + 3];
        float4 o;
        o.x = cb[(size_t)i0 * NC + c];
        o.y = cb[(size_t)i1 * NC + c];
        o.z = cb[(size_t)i2 * NC + c];
        o.w = cb[(size_t)i3 * NC + c];
        *(float4*)(outg + (size_t)c * HW + p4) = o;
        const float4 zv = *(const float4*)&z_lds[c][p4];
        const float d0 = o.x - zv.x;
        const float d1 = o.y - zv.y;
        const float d2 = o.z - zv.z;
        const float d3 = o.w - zv.w;
        lsum += d0 * d0 + d1 * d1 + d2 * d2 + d3 * d3;
    }
#pragma unroll
    for (int off = 32; off > 0; off >>= 1) lsum += __shfl_down(lsum, off, 64);
    if (lane == 0) red_v[wave][0] = lsum;
    __syncthreads();
    if (t == 0) {
        float s = 0.f;
#pragma unroll
        for (int w = 0; w < 4; ++w) s += red_v[w][0];
        atomicAdd(loss_acc + (blk & (NSLOT - 1)), (double)s);
    }
}

// ---------------------------------------------------------------------------
// Kernel D: loss = (1 + beta) * sum / NOUT
// ---------------------------------------------------------------------------
__global__ void finalize_kernel(const double* __restrict__ loss_acc,
                                float* __restrict__ out_loss) {
    if (threadIdx.x == 0) {
        double s = 0.0;
        for (int i = 0; i < NSLOT; ++i) s += loss_acc[i];
        *out_loss = (float)(1.25 * s / (double)NOUT);
    }
}

extern "C" void kernel_launch(void* const* d_in, const int* in_sizes, int n_in,
                              void* d_out, int out_size, void* d_ws, size_t ws_size,
                              hipStream_t stream) {
    const float* z = (const float*)d_in[0];
    const float* cb = (const float*)d_in[1];

    float* out = (float*)d_out;            // [16,256,64,64]
    float* loss_out = out + NOUT;          // scalar
    float* idx_out = out + NOUT + 1;       // [16,1,64,64] as float

    // workspace layout (~1.06 MB):
    //   [0, 2048)        : double loss_acc[NSLOT]
    //   [2048, 6144)     : float  cnorm[1024]
    //   [6144, 1054720)  : float  cbT3[64][8][128][4]
    double* loss_acc = (double*)d_ws;
    float* cnorm = (float*)((char*)d_ws + 2048);
    float* cbT3 = (float*)((char*)d_ws + 2048 + 4096);

    hipMemsetAsync(d_ws, 0, 2048, stream);
    cnorm_kernel<<<(NK + 255) / 256, 256, 0, stream>>>(cb, cnorm);
    pack_cb_kernel<<<NK, 256, 0, stream>>>(cb, cbT3);
    argmin_kernel<<<NPOS / TP, 256, 0, stream>>>(z, cb, cbT3, cnorm,
                                                 out, idx_out, loss_acc);
    finalize_kernel<<<1, 64, 0, stream>>>(loss_acc, loss_out);
}